// Round 4
// baseline (925.463 us; speedup 1.0000x reference)
//
#include <hip/hip_runtime.h>
#include <stdint.h>

#define NE 8
#define NI 2816
#define NH 1024
#define NT 8192
#define NPAIR (NT * 2)

typedef __bf16 bf16x8 __attribute__((ext_vector_type(8)));
typedef float f32x4 __attribute__((ext_vector_type(4)));

__device__ __forceinline__ uint16_t f2bf(float f) {
    union { float f; uint32_t u; } v;
    v.f = f;
    return (uint16_t)((v.u + 0x7FFFu + ((v.u >> 16) & 1u)) >> 16);
}

__device__ __forceinline__ float bflo(uint32_t u) {
    union { uint32_t x; float f; } v; v.x = u << 16; return v.f;
}
__device__ __forceinline__ float bfhi(uint32_t u) {
    union { uint32_t x; float f; } v; v.x = u & 0xffff0000u; return v.f;
}

// async global->LDS, 16B per lane. LDS dest must be lane-contiguous (wave-uniform
// base + lane*16). Generic->AS3 via 32-bit truncation (LDS aperture is 4GB-aligned).
__device__ __forceinline__ void gld16(const void* g, void* l) {
    __builtin_amdgcn_global_load_lds(
        (__attribute__((address_space(1))) void*)(uintptr_t)g,
        (__attribute__((address_space(3))) void*)(uint32_t)(uintptr_t)l,
        16, 0, 0);
}

// ---------------- weight conversion ----------------
// W1/W3 -> Wg interleaved: per expert, Wg row (r>>4)*32 + (W3?16:0) + (r&15)
// so a 256-wide N'-tile pairs 16 W1 cols with the same 16 W3 cols per n-frag pair.
__global__ __launch_bounds__(256) void k_cvt_w13(const float* __restrict__ W1,
                                                 const float* __restrict__ W3,
                                                 uint16_t* __restrict__ Wg) {
    int row = blockIdx.x * 2 + (threadIdx.x >> 7);   // 0 .. NE*NI-1
    int g = threadIdx.x & 127;                       // 8 floats per thread
    const float* src = (blockIdx.y == 0) ? W1 : W3;
    int e = row / NI;
    int r = row - e * NI;
    size_t drow = (size_t)e * (2 * NI) + (size_t)((r >> 4) * 32 + (r & 15) + (blockIdx.y ? 16 : 0));
    const float4* sp = (const float4*)(src + (size_t)row * NH);
    float4 a = sp[g * 2];
    float4 b = sp[g * 2 + 1];
    uint4 o;
    o.x = (uint32_t)f2bf(a.x) | ((uint32_t)f2bf(a.y) << 16);
    o.y = (uint32_t)f2bf(a.z) | ((uint32_t)f2bf(a.w) << 16);
    o.z = (uint32_t)f2bf(b.x) | ((uint32_t)f2bf(b.y) << 16);
    o.w = (uint32_t)f2bf(b.z) | ((uint32_t)f2bf(b.w) << 16);
    ((uint4*)(Wg + drow * NH))[g] = o;
}

__global__ __launch_bounds__(256) void k_cvt_flat(const float* __restrict__ S,
                                                  uint16_t* __restrict__ D) {
    size_t i = (size_t)blockIdx.x * 256 + threadIdx.x;
    float4 a = ((const float4*)S)[i * 2];
    float4 b = ((const float4*)S)[i * 2 + 1];
    uint4 o;
    o.x = (uint32_t)f2bf(a.x) | ((uint32_t)f2bf(a.y) << 16);
    o.y = (uint32_t)f2bf(a.z) | ((uint32_t)f2bf(a.w) << 16);
    o.z = (uint32_t)f2bf(b.x) | ((uint32_t)f2bf(b.y) << 16);
    o.w = (uint32_t)f2bf(b.z) | ((uint32_t)f2bf(b.w) << 16);
    ((uint4*)D)[i] = o;
}

// ---------------- router: top-2 of softmax, renormalized ----------------
__global__ __launch_bounds__(256) void k_router(const float* __restrict__ logits,
                                                int* __restrict__ tok_e,
                                                float2* __restrict__ tok_w,
                                                int* __restrict__ counts) {
    int t = blockIdx.x * 256 + threadIdx.x;
    if (t >= NT) return;
    float4 a = ((const float4*)logits)[(size_t)t * 2];
    float4 b = ((const float4*)logits)[(size_t)t * 2 + 1];
    float l[8] = {a.x, a.y, a.z, a.w, b.x, b.y, b.z, b.w};
    int i0 = 0; float l0 = l[0];
#pragma unroll
    for (int e = 1; e < 8; e++) if (l[e] > l0) { l0 = l[e]; i0 = e; }
    int i1 = -1; float l1 = -3.4e38f;
#pragma unroll
    for (int e = 0; e < 8; e++) if (e != i0 && l[e] > l1) { l1 = l[e]; i1 = e; }
    float w0 = 1.f / (1.f + __expf(l1 - l0));
    float w1 = 1.f - w0;
    tok_e[t] = i0 | (i1 << 8);
    tok_w[t] = make_float2(w0, w1);
    atomicAdd(&counts[i0], 1);
    atomicAdd(&counts[i1], 1);
}

__global__ void k_scan(const int* __restrict__ counts, int* __restrict__ offsets,
                       int* __restrict__ cursor) {
    if (threadIdx.x == 0) {
        int o = 0;
        for (int e = 0; e < NE; e++) { offsets[e] = o; cursor[e] = o; o += counts[e]; }
    }
}

// ---------------- gather routed x rows into per-expert bf16 panels ----------------
__global__ __launch_bounds__(128) void k_gather(const float* __restrict__ x,
                                                const int* __restrict__ tok_e,
                                                const float2* __restrict__ tok_w,
                                                int* __restrict__ cursor,
                                                uint16_t* __restrict__ Xg,
                                                int2* __restrict__ tok_slots,
                                                float* __restrict__ slot_w) {
    int t = blockIdx.x;
    __shared__ int ss[2];
    if (threadIdx.x == 0) {
        int ee = tok_e[t];
        float2 w = tok_w[t];
        int s0 = atomicAdd(&cursor[ee & 0xff], 1);
        int s1 = atomicAdd(&cursor[(ee >> 8) & 0xff], 1);
        ss[0] = s0; ss[1] = s1;
        tok_slots[t] = make_int2(s0, s1);
        slot_w[s0] = w.x;
        slot_w[s1] = w.y;
    }
    __syncthreads();
    int s0 = ss[0], s1 = ss[1];
    int i = threadIdx.x;
    const float4* xr = (const float4*)(x + (size_t)t * NH);
    float4 a = xr[i * 2];
    float4 b = xr[i * 2 + 1];
    uint4 o;
    o.x = (uint32_t)f2bf(a.x) | ((uint32_t)f2bf(a.y) << 16);
    o.y = (uint32_t)f2bf(a.z) | ((uint32_t)f2bf(a.w) << 16);
    o.z = (uint32_t)f2bf(b.x) | ((uint32_t)f2bf(b.y) << 16);
    o.w = (uint32_t)f2bf(b.z) | ((uint32_t)f2bf(b.w) << 16);
    ((uint4*)(Xg + (size_t)s0 * NH))[i] = o;
    ((uint4*)(Xg + (size_t)s1 * NH))[i] = o;
}

// ================= gemm1: 256x256 8-phase, deep-pipelined =================
// Hbuf = silu(X@W1^T)*(X@W3^T) via interleaved Wg, N'=5632, K=1024
// 512 threads = 8 waves (2M x 4N), per-wave C = 128x64. LDS 128 KiB.
// See round-3 notes: vmcnt(6) FIFO checkpoints at P4/P8; WAITV0 before epilogue.

#define BAR()  asm volatile("s_barrier" ::: "memory")
#define WAITLGKM0 asm volatile("s_waitcnt lgkmcnt(0)" ::: "memory")
#define WAITLGKM4 asm volatile("s_waitcnt lgkmcnt(4)" ::: "memory")
#define WAITV6 asm volatile("s_waitcnt vmcnt(6)" ::: "memory")
#define WAITV2 asm volatile("s_waitcnt vmcnt(2)" ::: "memory")
#define WAITV0 asm volatile("s_waitcnt vmcnt(0)" ::: "memory")
#define SCHB __builtin_amdgcn_sched_barrier(0)
#define PRIO1 __builtin_amdgcn_s_setprio(1)
#define PRIO0 __builtin_amdgcn_s_setprio(0)

// stage one 128x64 half-tile (16 KiB): linear LDS dest, inverse-swizzled global src
#define STAGE(ab, bufsel, h, kt)                                                  \
    do {                                                                          \
        char* d_ = lds + (bufsel) * 65536 + (ab) * 32768 + (h) * 16384 + tid * 16; \
        gld16(((ab) ? srcB : srcA)[h][0] + (kt) * 64, d_);                         \
        gld16(((ab) ? srcB : srcA)[h][1] + (kt) * 64, d_ + 8192);                  \
    } while (0)

// A frags for m-quadrant mh (4 m-frags x 2 k-slices); wave wr reads only half wr
#define READA(bufsel, mh)                                                           \
    do {                                                                            \
        _Pragma("unroll") for (int ii = 0; ii < 4; ii++) {                          \
            const char* p_ = lds + (bufsel) * 65536 + wr * 16384 +                  \
                             (((mh) * 4 + ii) * 16 + l15) * 128;                    \
            af[ii][0] = *(const bf16x8*)(p_ + colk0);                               \
            af[ii][1] = *(const bf16x8*)(p_ + colk1);                               \
        }                                                                           \
    } while (0)

// B frags for n-half nh (2 n-frags x 2 k-slices) into dst
#define READB(bufsel, nh, dst)                                                      \
    do {                                                                            \
        _Pragma("unroll") for (int jj = 0; jj < 2; jj++) {                          \
            int gb_ = wc * 64 + ((nh) * 2 + jj) * 16;                               \
            const char* p_ = lds + (bufsel) * 65536 + 32768 + (gb_ >> 7) * 16384 +  \
                             ((gb_ & 127) + l15) * 128;                             \
            dst[jj][0] = *(const bf16x8*)(p_ + colk0);                              \
            dst[jj][1] = *(const bf16x8*)(p_ + colk1);                              \
        }                                                                           \
    } while (0)

// one C-quadrant: 4 m-frags x 2 n-frags x K=64  (16 MFMA)
#define MMQ(mh, bsrc, jb)                                                           \
    do {                                                                            \
        _Pragma("unroll") for (int ii = 0; ii < 4; ii++)                            \
            _Pragma("unroll") for (int jj = 0; jj < 2; jj++)                        \
                _Pragma("unroll") for (int ks = 0; ks < 2; ks++)                    \
                    acc[(mh) * 4 + ii][(jb) + jj] =                                 \
                        __builtin_amdgcn_mfma_f32_16x16x32_bf16(                    \
                            af[ii][ks], bsrc[jj][ks], acc[(mh) * 4 + ii][(jb) + jj],\
                            0, 0, 0);                                               \
    } while (0)

__global__ __launch_bounds__(512, 2) void k_gemm1(const uint16_t* __restrict__ Abase,
                                                  const uint16_t* __restrict__ Bbase,
                                                  uint16_t* __restrict__ Cbase,
                                                  const int* __restrict__ counts,
                                                  const int* __restrict__ offsets) {
    constexpr int K = NH;           // 1024
    constexpr int NKT = K / 64;     // 16
    constexpr int NITER = NKT / 2;  // 8
    constexpr int BROWS = 2 * NI;
    constexpr int CLD = NI;
    constexpr int GX = 2 * NI / 256, GY = NT / 256;  // 22, 32
    constexpr int CPX = GX * GY * NE / 8;            // 704

    // XCD-chunk swizzle (T1, bijective: 8 | nwg): XCD k gets contiguous work chunk.
    int lin = blockIdx.x + GX * (blockIdx.y + GY * blockIdx.z);
    int w = (lin & 7) * CPX + (lin >> 3);
    int ntile = w % GX;
    int rem = w / GX;
    int mtile = rem % GY;
    int e = rem / GY;

    int n_e = counts[e];
    if (mtile * 256 >= n_e) return;
    int off = offsets[e];

    __shared__ __align__(16) char lds[131072];

    int tid = threadIdx.x;
    int l15 = tid & 15;
    int q = (tid >> 4) & 3;
    int x7 = tid & 7;
    int wv = tid >> 6, wr = wv >> 2, wc = wv & 3;
    int colk0 = (q ^ x7) << 4;         // swizzled byte col, k-slice 0
    int colk1 = ((q + 4) ^ x7) << 4;   // k-slice 1

    int sr = tid >> 3;
    int ss = x7 ^ (sr & 7);
    const uint16_t* srcA[2][2];
    const uint16_t* srcB[2][2];
#pragma unroll
    for (int h = 0; h < 2; h++)
#pragma unroll
        for (int j = 0; j < 2; j++) {
            int gr = off + mtile * 256 + h * 128 + j * 64 + sr;
            gr = min(gr, NPAIR - 1);  // tail rows: read valid garbage, masked at store
            srcA[h][j] = Abase + (size_t)gr * K + ss * 8;
            int gn = ntile * 256 + h * 128 + j * 64 + sr;
            srcB[h][j] = Bbase + (size_t)e * BROWS * K + (size_t)gn * K + ss * 8;
        }

    bf16x8 af[4][2], b0[2][2], b1[2][2];
    f32x4 acc[8][4] = {};

    // prologue = steady-state stage FIFO of a virtual previous iteration
    STAGE(1, 0, 0, 0);
    STAGE(1, 0, 1, 0);
    STAGE(0, 0, 0, 0);
    STAGE(0, 0, 1, 0);
    STAGE(1, 1, 0, 1);
    STAGE(1, 1, 1, 1);
    STAGE(0, 1, 0, 1);
    WAITV6;
    BAR();

#pragma unroll 1
    for (int it = 0; it < NITER; ++it) {
        int kt1 = 2 * it + 1;
        int kt2 = min(2 * it + 2, NKT - 1);
        int kt3 = min(2 * it + 3, NKT - 1);
        // ---- P1 ----
        READA(0, 0);
        READB(0, 0, b0);
        READB(0, 1, b1);
        STAGE(0, 1, 1, kt1);
        WAITLGKM4; SCHB; PRIO1; MMQ(0, b0, 0); PRIO0; SCHB;
        BAR();
        // ---- P2 ----
        STAGE(1, 0, 0, kt2);
        WAITLGKM0; SCHB; PRIO1; MMQ(0, b1, 2); PRIO0; SCHB;
        READA(0, 1);
        BAR();
        // ---- P3 ----
        STAGE(1, 0, 1, kt2);
        WAITLGKM0; SCHB; PRIO1; MMQ(1, b1, 2); PRIO0; SCHB;
        BAR();
        // ---- P4 ----
        STAGE(0, 0, 0, kt2);
        PRIO1; MMQ(1, b0, 0); PRIO0; SCHB;
        WAITV6;
        BAR();
        // ---- P5 ----
        READA(1, 0);
        READB(1, 0, b0);
        READB(1, 1, b1);
        STAGE(0, 0, 1, kt2);
        WAITLGKM4; SCHB; PRIO1; MMQ(0, b0, 0); PRIO0; SCHB;
        BAR();
        // ---- P6 ----
        STAGE(1, 1, 0, kt3);
        WAITLGKM0; SCHB; PRIO1; MMQ(0, b1, 2); PRIO0; SCHB;
        READA(1, 1);
        BAR();
        // ---- P7 ----
        STAGE(1, 1, 1, kt3);
        WAITLGKM0; SCHB; PRIO1; MMQ(1, b1, 2); PRIO0; SCHB;
        BAR();
        // ---- P8 ----
        STAGE(0, 1, 0, kt3);
        PRIO1; MMQ(1, b0, 0); PRIO0; SCHB;
        WAITV6;
        BAR();
    }

    WAITV0;  // drain tail LDS-DMA before epilogue/endpgm

    // epilogue: silu(c1)*c3 on interleaved fragment pairs
    int sBase = off + mtile * 256;
#pragma unroll
    for (int im = 0; im < 8; im++) {
#pragma unroll
        for (int r = 0; r < 4; r++) {
            int lm = wr * 128 + im * 16 + q * 4 + r;
            if (mtile * 256 + lm < n_e) {
                uint16_t* orow = Cbase + (size_t)(sBase + lm) * CLD +
                                 ntile * 128 + wc * 32 + l15;
#pragma unroll
                for (int j = 0; j < 2; j++) {
                    float c1 = acc[im][2 * j][r];
                    float c3 = acc[im][2 * j + 1][r];
                    float hv = (c1 / (1.f + __expf(-c1))) * c3;
                    orow[j * 16] = f2bf(hv);
                }
            }
        }
    }
}

// ================= gemm2b: 64x256 tile, 4 waves, 2 blocks/CU =================
// Ybuf = H @ W2^T. 256 threads = 4 waves (1M x 4N), per-wave C = 64x64.
// LDS 80 KiB = 2 sets x {A 8 KiB (64rx64k), B 32 KiB (256rx64k)}, XOR-swizzled.
// 4 phases / 2 K-tiles; vmcnt(2) checkpoints at P2/P4 (FIFO: retires exactly the
// other set's 10 staging loads, leaving the newest A-stage in flight).
// 2 blocks/CU: independent blocks hide each other's checkpoint stalls.

#define G2STAGE_A(s, kt)                                                     \
    do {                                                                     \
        char* d_ = lds2 + (s) * 40960 + tid * 16;                            \
        gld16(pA0 + (kt) * 64, d_);                                          \
        gld16(pA1 + (kt) * 64, d_ + 4096);                                   \
    } while (0)
#define G2STAGE_BH(s, h, kt)                                                 \
    do {                                                                     \
        char* d_ = lds2 + (s) * 40960 + 8192 + (h) * 16384 + tid * 16;       \
        gld16(pB[(h) * 4 + 0] + (kt) * 64, d_);                              \
        gld16(pB[(h) * 4 + 1] + (kt) * 64, d_ + 4096);                       \
        gld16(pB[(h) * 4 + 2] + (kt) * 64, d_ + 8192);                       \
        gld16(pB[(h) * 4 + 3] + (kt) * 64, d_ + 12288);                      \
    } while (0)
#define G2READA(s)                                                           \
    do {                                                                     \
        _Pragma("unroll") for (int ii = 0; ii < 4; ii++) {                   \
            const char* p_ = lds2 + (s) * 40960 + (ii * 16 + l15) * 128;     \
            af[ii][0] = *(const bf16x8*)(p_ + colk0);                        \
            af[ii][1] = *(const bf16x8*)(p_ + colk1);                        \
        }                                                                    \
    } while (0)
#define G2READB(s, h)                                                        \
    do {                                                                     \
        _Pragma("unroll") for (int jj = 0; jj < 2; jj++) {                   \
            const char* p_ = lds2 + (s) * 40960 + 8192 +                     \
                             (wv * 64 + ((h) * 2 + jj) * 16 + l15) * 128;    \
            bf[(h) * 2 + jj][0] = *(const bf16x8*)(p_ + colk0);              \
            bf[(h) * 2 + jj][1] = *(const bf16x8*)(p_ + colk1);              \
        }                                                                    \
    } while (0)
#define G2MMQ(h)                                                             \
    do {                                                                     \
        _Pragma("unroll") for (int ii = 0; ii < 4; ii++)                     \
            _Pragma("unroll") for (int jj = 0; jj < 2; jj++)                 \
                _Pragma("unroll") for (int ks = 0; ks < 2; ks++)             \
                    acc[ii][(h) * 2 + jj] =                                  \
                        __builtin_amdgcn_mfma_f32_16x16x32_bf16(             \
                            af[ii][ks], bf[(h) * 2 + jj][ks],                \
                            acc[ii][(h) * 2 + jj], 0, 0, 0);                 \
    } while (0)

__global__ __launch_bounds__(256, 2) void k_gemm2b(const uint16_t* __restrict__ Hbuf,
                                                   const uint16_t* __restrict__ W2b,
                                                   uint16_t* __restrict__ Ybuf,
                                                   const int* __restrict__ counts,
                                                   const int* __restrict__ offsets) {
    constexpr int K = NI;           // 2816
    constexpr int NKT = K / 64;     // 44
    constexpr int NITER = NKT / 2;  // 22
    constexpr int GX = NT / 64, GY = NH / 256;  // 128, 4
    constexpr int CPX = GX * GY * NE / 8;       // 512

    // XCD-chunk swizzle: consecutive work units share (e, ntile) B panel (1.44 MB,
    // L2-resident per XCD).
    int lin = blockIdx.x + GX * (blockIdx.y + GY * blockIdx.z);
    int w = (lin & 7) * CPX + (lin >> 3);
    int mtile = w % GX;
    int rem = w / GX;
    int ntile = rem % GY;
    int e = rem / GY;

    int n_e = counts[e];
    if (mtile * 64 >= n_e) return;
    int off = offsets[e];

    __shared__ __align__(16) char lds2[81920];

    int tid = threadIdx.x;
    int l15 = tid & 15;
    int q = (tid >> 4) & 3;
    int x7 = tid & 7;
    int wv = tid >> 6;
    int colk0 = (q ^ x7) << 4;
    int colk1 = ((q + 4) ^ x7) << 4;

    int sr = tid >> 3;          // staging row 0..31
    int ss = x7 ^ (sr & 7);     // inverse-swizzled source slot
    int ra0 = min(off + mtile * 64 + sr, NPAIR - 1);
    int ra1 = min(off + mtile * 64 + 32 + sr, NPAIR - 1);
    const uint16_t* pA0 = Hbuf + (size_t)ra0 * K + ss * 8;
    const uint16_t* pA1 = Hbuf + (size_t)ra1 * K + ss * 8;
    const uint16_t* pB[8];
#pragma unroll
    for (int j = 0; j < 8; j++)
        pB[j] = W2b + ((size_t)e * NH + ntile * 256 + j * 32 + sr) * K + ss * 8;

    bf16x8 af[4][2], bf[4][2];
    f32x4 acc[4][4] = {};

    // prologue: s0 <- tile0 (A, Bh0, Bh1), s1.A <- tile1; 12 issued, retire to 2.
    G2STAGE_A(0, 0);
    G2STAGE_BH(0, 0, 0);
    G2STAGE_BH(0, 1, 0);
    G2STAGE_A(1, 1);
    WAITV2;
    BAR();

#pragma unroll 1
    for (int it = 0; it < NITER; ++it) {
        int kt1 = 2 * it + 1;
        int kt2 = min(2 * it + 2, NKT - 1);
        int kt3 = min(2 * it + 3, NKT - 1);
        // ---- P1 ---- reads s0 (A 8, B01 4, B23 4); stage s1.Bh0 <- kt1
        G2READA(0); G2READB(0, 0); G2READB(0, 1);
        G2STAGE_BH(1, 0, kt1);
        WAITLGKM4; SCHB; PRIO1; G2MMQ(0); PRIO0; SCHB;
        BAR();
        // ---- P2 ---- stage s1.Bh1 <- kt1, s0.A <- kt2; MFMA B23; checkpoint s1
        G2STAGE_BH(1, 1, kt1);
        G2STAGE_A(0, kt2);
        WAITLGKM0; SCHB; PRIO1; G2MMQ(1); PRIO0; SCHB;
        WAITV2;
        BAR();
        // ---- P3 ---- reads s1; stage s0.Bh0 <- kt2
        G2READA(1); G2READB(1, 0); G2READB(1, 1);
        G2STAGE_BH(0, 0, kt2);
        WAITLGKM4; SCHB; PRIO1; G2MMQ(0); PRIO0; SCHB;
        BAR();
        // ---- P4 ---- stage s0.Bh1 <- kt2, s1.A <- kt3; MFMA B23; checkpoint s0
        G2STAGE_BH(0, 1, kt2);
        G2STAGE_A(1, kt3);
        WAITLGKM0; SCHB; PRIO1; G2MMQ(1); PRIO0; SCHB;
        WAITV2;
        BAR();
    }

    WAITV0;  // drain tail LDS-DMA before epilogue/endpgm

    int sBase = off + mtile * 64;
#pragma unroll
    for (int im = 0; im < 4; im++) {
#pragma unroll
        for (int r = 0; r < 4; r++) {
            int lm = im * 16 + q * 4 + r;
            if (mtile * 64 + lm < n_e) {
                uint16_t* orow = Ybuf + (size_t)(sBase + lm) * NH +
                                 ntile * 256 + wv * 64 + l15;
#pragma unroll
                for (int jn = 0; jn < 4; jn++) orow[jn * 16] = f2bf(acc[im][jn][r]);
            }
        }
    }
}

// ---------------- combine: out[t] = w0*Y[s0] + w1*Y[s1] (fp32) ----------------
__global__ __launch_bounds__(256) void k_combine(const uint16_t* __restrict__ Y,
                                                 const int2* __restrict__ tok_slots,
                                                 const float* __restrict__ slot_w,
                                                 float* __restrict__ out) {
    int idx = blockIdx.x * 256 + threadIdx.x;
    int t = idx >> 7;
    int g = idx & 127;
    int2 s = tok_slots[t];
    float w0 = slot_w[s.x], w1 = slot_w[s.y];
    uint4 u0 = ((const uint4*)(Y + (size_t)s.x * NH))[g];
    uint4 u1 = ((const uint4*)(Y + (size_t)s.y * NH))[g];
    float4 o0, o1;
    o0.x = w0 * bflo(u0.x) + w1 * bflo(u1.x);
    o0.y = w0 * bfhi(u0.x) + w1 * bfhi(u1.x);
    o0.z = w0 * bflo(u0.y) + w1 * bflo(u1.y);
    o0.w = w0 * bfhi(u0.y) + w1 * bfhi(u1.y);
    o1.x = w0 * bflo(u0.z) + w1 * bflo(u1.z);
    o1.y = w0 * bfhi(u0.z) + w1 * bfhi(u1.z);
    o1.z = w0 * bflo(u0.w) + w1 * bflo(u1.w);
    o1.w = w0 * bfhi(u0.w) + w1 * bfhi(u1.w);
    float4* orow = (float4*)(out + (size_t)t * NH + g * 8);
    orow[0] = o0;
    orow[1] = o1;
}

extern "C" void kernel_launch(void* const* d_in, const int* in_sizes, int n_in,
                              void* d_out, int out_size, void* d_ws, size_t ws_size,
                              hipStream_t stream) {
    const float* x = (const float*)d_in[0];
    const float* logits = (const float*)d_in[1];
    const float* W1 = (const float*)d_in[2];
    const float* W3 = (const float*)d_in[3];
    const float* W2 = (const float*)d_in[4];
    float* out = (float*)d_out;

    char* ws = (char*)d_ws;
    size_t o = 0;
    auto nxt = [&](size_t b) -> void* {
        void* p = ws + o;
        o += (b + 255) & ~(size_t)255;
        return p;
    };
    const size_t WELEMS = (size_t)NE * NI * NH;
    uint16_t* Wg = (uint16_t*)nxt(WELEMS * 2 * 2);   // interleaved W1/W3 (2x size)
    uint16_t* W2b = (uint16_t*)nxt(WELEMS * 2);
    uint16_t* Xg = (uint16_t*)nxt((size_t)NPAIR * NH * 2);  // aliased as Ybuf after gemm1
    uint16_t* Hbuf = (uint16_t*)nxt((size_t)NPAIR * NI * 2);
    float* slot_w = (float*)nxt((size_t)NPAIR * 4);
    int2* tok_slots = (int2*)nxt((size_t)NT * 8);
    int* tok_e = (int*)nxt((size_t)NT * 4);
    float2* tok_w = (float2*)nxt((size_t)NT * 8);
    int* meta = (int*)nxt(128);
    int* counts = meta;
    int* offsets = meta + 8;
    int* cursor = meta + 16;
    uint16_t* Ybuf = Xg;
    (void)ws_size; (void)in_sizes; (void)n_in;

    hipMemsetAsync(meta, 0, 128, stream);

    k_router<<<NT / 256, 256, 0, stream>>>(logits, tok_e, tok_w, counts);
    k_scan<<<1, 64, 0, stream>>>(counts, offsets, cursor);

    k_cvt_w13<<<dim3(NE * NI / 2, 2), 256, 0, stream>>>(W1, W3, Wg);
    k_cvt_flat<<<(unsigned)(WELEMS / 8 / 256), 256, 0, stream>>>(W2, W2b);

    k_gather<<<NT, 128, 0, stream>>>(x, tok_e, tok_w, cursor, Xg, tok_slots, slot_w);

    // gemm1: N' = 2*NI = 5632 -> 22 ntiles, 256-row mtiles
    k_gemm1<<<dim3(2 * NI / 256, NT / 256, NE), 512, 0, stream>>>(
        Xg, Wg, Hbuf, counts, offsets);
    // gemm2: 64-row mtiles x 256-col ntiles, 2 blocks/CU
    k_gemm2b<<<dim3(NT / 64, NH / 256, NE), 256, 0, stream>>>(
        Hbuf, W2b, Ybuf, counts, offsets);

    k_combine<<<NT * NH / 8 / 256, 256, 0, stream>>>(Ybuf, tok_slots, slot_w, out);
}